// Round 1
// baseline (439.466 us; speedup 1.0000x reference)
//
#include <hip/hip_runtime.h>
#include <stdint.h>

#define TT 4096      // tokens
#define DM 1024      // d_model
#define NE 16        // experts
#define DFF 512      // per-expert ffn
#define DFS 1024     // shared ffn
#define CAP 1024     // capacity

typedef unsigned short u16;
typedef __bf16 bf16x8 __attribute__((ext_vector_type(8)));
typedef float f32x4 __attribute__((ext_vector_type(4)));

typedef __attribute__((address_space(1))) void as1_void;
typedef __attribute__((address_space(3))) void as3_void;

__device__ __forceinline__ u16 f2bf(float f) {
  union { float f; uint32_t u; } v; v.f = f;
  uint32_t u = v.u;
  u += 0x7fffu + ((u >> 16) & 1u);   // RNE
  return (u16)(u >> 16);
}

__device__ __forceinline__ void gl2lds16(const void* g, void* l) {
  __builtin_amdgcn_global_load_lds(
      (as1_void*)(uintptr_t)g,
      (as3_void*)(uint32_t)(uintptr_t)l,
      16, 0, 0);
}

// ---------------- fp32 -> bf16 flat convert ----------------
__global__ __launch_bounds__(256) void k_cvt_bf16(const float4* __restrict__ in,
                                                  ushort4* __restrict__ out, int n4) {
  int i = blockIdx.x * 256 + threadIdx.x;
  if (i >= n4) return;
  float4 v = in[i];
  ushort4 o;
  o.x = f2bf(v.x); o.y = f2bf(v.y); o.z = f2bf(v.z); o.w = f2bf(v.w);
  out[i] = o;
}

// ---------------- fp32 [R,C] -> bf16 [C,R] transpose-convert (batched on z) ----------------
__global__ __launch_bounds__(256) void k_tr_cvt(const float* __restrict__ in,
                                                u16* __restrict__ out, int R, int C) {
  __shared__ float tile[32][33];
  size_t mb = (size_t)blockIdx.z * (size_t)R * (size_t)C;
  const float* ip = in + mb;
  u16* op = out + mb;
  int c0 = blockIdx.x * 32, r0 = blockIdx.y * 32;
  int tx = threadIdx.x & 31, ty = threadIdx.x >> 5;   // 32x8
#pragma unroll
  for (int j = 0; j < 4; ++j)
    tile[ty + 8 * j][tx] = ip[(size_t)(r0 + ty + 8 * j) * C + (c0 + tx)];
  __syncthreads();
#pragma unroll
  for (int j = 0; j < 4; ++j)
    op[(size_t)(c0 + ty + 8 * j) * R + (r0 + tx)] = f2bf(tile[tx][ty + 8 * j]);
}

// ---------------- router: fp32 logits, top-2, slot assignment ----------------
__global__ __launch_bounds__(256) void k_router(const float* __restrict__ x,
                                                const float* __restrict__ Wg,
                                                int* __restrict__ counts,
                                                int* __restrict__ tok_slot,
                                                float* __restrict__ wgt_slot) {
  __shared__ float lg[16][17];
  int e = threadIdx.x & 15, tl = threadIdx.x >> 4;
  int t = blockIdx.x * 16 + tl;
  const float* xr = x + (size_t)t * DM;
  float acc = 0.f;
  for (int d = 0; d < DM; d += 4) {
    float4 xv = *(const float4*)(xr + d);
    acc += xv.x * Wg[(d    ) * NE + e];
    acc += xv.y * Wg[(d + 1) * NE + e];
    acc += xv.z * Wg[(d + 2) * NE + e];
    acc += xv.w * Wg[(d + 3) * NE + e];
  }
  lg[tl][e] = acc;
  __syncthreads();
  if (e == 0) {
    float b0 = -1e30f; int i0 = 0;
#pragma unroll
    for (int i = 0; i < NE; ++i) { float v = lg[tl][i]; if (v > b0) { b0 = v; i0 = i; } }
    float b1 = -1e30f; int i1 = 0;
#pragma unroll
    for (int i = 0; i < NE; ++i) { if (i == i0) continue; float v = lg[tl][i]; if (v > b1) { b1 = v; i1 = i; } }
    // renormalized top-2 softmax weights (denominator cancels)
    float ex = __expf(b1 - b0);
    float w0 = 1.f / (1.f + ex);
    float w1 = 1.f - w0;
    int p0 = atomicAdd(&counts[i0], 1);
    if (p0 < CAP) { int s = i0 * CAP + p0; tok_slot[s] = t; wgt_slot[s] = w0; }
    int p1 = atomicAdd(&counts[i1], 1);
    if (p1 < CAP) { int s = i1 * CAP + p1; tok_slot[s] = t; wgt_slot[s] = w1; }
  }
}

// ---------------- GEMM: 128x128 tile, BK=32, 16x16x32 bf16 MFMA ----------------
// A: [M,K] bf16 row-major (MODE 1: gathered rows of hidden via tok_slot)
// B: [N,K] bf16 row-major (pre-transposed)
// MODE 0: dual-B (B1,B3), epilogue silu(a1)*a3 -> bf16 Cbf          (shared up)
// MODE 1: as 0, per-expert (z), A gathered, early-exit on count      (routed up)
// MODE 2: single-B, fp32 store to Cf                                 (shared down)
// MODE 3: single-B, per-expert, atomicAdd(w * acc) scatter to Cf     (routed down)
template <int MODE>
__global__ __launch_bounds__(256) void k_gemm(
    const u16* __restrict__ A, const u16* __restrict__ B1, const u16* __restrict__ B3,
    u16* __restrict__ Cbf, float* __restrict__ Cf,
    const int* __restrict__ counts, const int* __restrict__ tok_slot,
    const float* __restrict__ wgt_slot, int M, int N, int K) {
  constexpr bool DUAL = (MODE == 0 || MODE == 1);
  const int z = blockIdx.z;
  const int m0 = blockIdx.y * 128;
  const int n0 = blockIdx.x * 128;
  const int tid = threadIdx.x;

  int cnt = M;
  if constexpr (MODE == 1 || MODE == 3) {
    cnt = counts[z]; if (cnt > CAP) cnt = CAP;
    if (m0 >= cnt) return;            // uniform exit, before any barrier
  }

  const u16* Ap = A;
  const u16* B1p = B1;
  const u16* B3p = B3;
  u16* Cbfp = Cbf;
  if constexpr (MODE == 1) {
    B1p = B1 + (size_t)z * DFF * DM;
    B3p = B3 + (size_t)z * DFF * DM;
    Cbfp = Cbf + (size_t)z * CAP * DFF;
  }
  if constexpr (MODE == 3) {
    Ap = A + (size_t)z * CAP * DFF;
    B1p = B1 + (size_t)z * DM * DFF;
  }

  __shared__ u16 As[128 * 32];
  __shared__ u16 Bs1[128 * 32];
  __shared__ u16 Bs3[DUAL ? 128 * 32 : 8];

  const int srow = tid >> 2;          // staged row 0..63 (and +64)
  const int kc = (tid & 3) * 8;       // k offset within BK
  size_t aoff0, aoff1;
  if constexpr (MODE == 1) {
    int r0 = m0 + srow, r1 = r0 + 64;
    int t0 = (r0 < cnt) ? tok_slot[z * CAP + r0] : 0;
    int t1 = (r1 < cnt) ? tok_slot[z * CAP + r1] : 0;
    aoff0 = (size_t)t0 * K + kc;
    aoff1 = (size_t)t1 * K + kc;
  } else {
    aoff0 = (size_t)(m0 + srow) * K + kc;
    aoff1 = aoff0 + (size_t)64 * K;
  }
  const size_t boff0 = (size_t)(n0 + srow) * K + kc;
  const size_t boff1 = boff0 + (size_t)64 * K;

  const int lane = tid & 63;
  const int wv = tid >> 6;
  const int wr = (wv >> 1) * 64;      // wave row origin
  const int wc = (wv & 1) * 64;       // wave col origin
  const int lr = lane & 15;
  const int lq = lane >> 4;

  f32x4 acc1[4][4];
  f32x4 acc3[4][4];
#pragma unroll
  for (int i = 0; i < 4; ++i)
#pragma unroll
    for (int j = 0; j < 4; ++j) {
      acc1[i][j] = (f32x4){0.f, 0.f, 0.f, 0.f};
      if constexpr (DUAL) acc3[i][j] = (f32x4){0.f, 0.f, 0.f, 0.f};
    }

  for (int k0 = 0; k0 < K; k0 += 32) {
    __syncthreads();
    gl2lds16(Ap + aoff0 + k0, &As[(size_t)tid * 8]);
    gl2lds16(Ap + aoff1 + k0, &As[(size_t)(tid + 256) * 8]);
    gl2lds16(B1p + boff0 + k0, &Bs1[(size_t)tid * 8]);
    gl2lds16(B1p + boff1 + k0, &Bs1[(size_t)(tid + 256) * 8]);
    if constexpr (DUAL) {
      gl2lds16(B3p + boff0 + k0, &Bs3[(size_t)tid * 8]);
      gl2lds16(B3p + boff1 + k0, &Bs3[(size_t)(tid + 256) * 8]);
    }
    __syncthreads();
    bf16x8 af[4], bf1[4], bf3[4];
#pragma unroll
    for (int i = 0; i < 4; ++i)
      af[i] = *(const bf16x8*)&As[(wr + i * 16 + lr) * 32 + lq * 8];
#pragma unroll
    for (int j = 0; j < 4; ++j) {
      bf1[j] = *(const bf16x8*)&Bs1[(wc + j * 16 + lr) * 32 + lq * 8];
      if constexpr (DUAL) bf3[j] = *(const bf16x8*)&Bs3[(wc + j * 16 + lr) * 32 + lq * 8];
    }
#pragma unroll
    for (int i = 0; i < 4; ++i)
#pragma unroll
      for (int j = 0; j < 4; ++j) {
        acc1[i][j] = __builtin_amdgcn_mfma_f32_16x16x32_bf16(af[i], bf1[j], acc1[i][j], 0, 0, 0);
        if constexpr (DUAL)
          acc3[i][j] = __builtin_amdgcn_mfma_f32_16x16x32_bf16(af[i], bf3[j], acc3[i][j], 0, 0, 0);
      }
  }

  // ---- epilogue ----  D row = m0+wr+i*16+lq*4+r, col = n0+wc+j*16+lr
  if constexpr (MODE == 0 || MODE == 1) {
#pragma unroll
    for (int i = 0; i < 4; ++i)
#pragma unroll
      for (int r = 0; r < 4; ++r) {
        int row = m0 + wr + i * 16 + lq * 4 + r;
        u16* crow = Cbfp + (size_t)row * N;
#pragma unroll
        for (int j = 0; j < 4; ++j) {
          float v1 = acc1[i][j][r];
          float v3 = acc3[i][j][r];
          float h = (v1 / (1.f + __expf(-v1))) * v3;   // silu(v1)*v3
          crow[n0 + wc + j * 16 + lr] = f2bf(h);
        }
      }
  } else if constexpr (MODE == 2) {
#pragma unroll
    for (int i = 0; i < 4; ++i)
#pragma unroll
      for (int r = 0; r < 4; ++r) {
        int row = m0 + wr + i * 16 + lq * 4 + r;
        float* crow = Cf + (size_t)row * N;
#pragma unroll
        for (int j = 0; j < 4; ++j)
          crow[n0 + wc + j * 16 + lr] = acc1[i][j][r];
      }
  } else {  // MODE 3: weighted scatter-add
#pragma unroll
    for (int i = 0; i < 4; ++i)
#pragma unroll
      for (int r = 0; r < 4; ++r) {
        int row = m0 + wr + i * 16 + lq * 4 + r;
        if (row < cnt) {
          int slot = z * CAP + row;
          int t = tok_slot[slot];
          float w = wgt_slot[slot];
          float* orow = Cf + (size_t)t * N;
#pragma unroll
          for (int j = 0; j < 4; ++j)
            atomicAdd(&orow[n0 + wc + j * 16 + lr], w * acc1[i][j][r]);
        }
      }
  }
}

// ---------------- host ----------------
extern "C" void kernel_launch(void* const* d_in, const int* in_sizes, int n_in,
                              void* d_out, int out_size, void* d_ws, size_t ws_size,
                              hipStream_t stream) {
  (void)in_sizes; (void)n_in; (void)out_size; (void)ws_size;
  const float* x   = (const float*)d_in[0];
  const float* Wg  = (const float*)d_in[1];
  const float* w1  = (const float*)d_in[2];
  const float* w3  = (const float*)d_in[3];
  const float* w2  = (const float*)d_in[4];
  const float* ws1 = (const float*)d_in[5];
  const float* ws3 = (const float*)d_in[6];
  const float* ws2 = (const float*)d_in[7];
  // d_in[8] = capacity (device scalar); fixed at 1024 per problem spec
  float* out = (float*)d_out;
  char* ws = (char*)d_ws;

  u16* hbf   = (u16*)(ws + 0);          // 8,388,608 B  [TT,DM] bf16
  u16* w1t   = (u16*)(ws + 8388608);    // 16,777,216 B [E][DFF][DM]
  u16* w3t   = (u16*)(ws + 25165824);   // 16,777,216 B
  u16* w2t   = (u16*)(ws + 41943040);   // 16,777,216 B [E][DM][DFF]
  u16* ws1t  = (u16*)(ws + 58720256);   // 2,097,152 B  [DFS][DM]
  u16* ws3t  = (u16*)(ws + 60817408);   // 2,097,152 B
  u16* ws2t  = (u16*)(ws + 62914560);   // 2,097,152 B  [DM][DFS]
  u16* hs    = (u16*)(ws + 65011712);   // 8,388,608 B  [TT,DFS] bf16
  u16* hexp  = (u16*)(ws + 73400320);   // 16,777,216 B [E][CAP][DFF] bf16
  int* counts    = (int*)(ws + 90177536);
  int* tok_slot  = (int*)(ws + 90177792);
  float* wgt_slot = (float*)(ws + 90243328);

  hipMemsetAsync(counts, 0, NE * sizeof(int), stream);

  k_cvt_bf16<<<dim3((TT * DM / 4) / 256), dim3(256), 0, stream>>>(
      (const float4*)x, (ushort4*)hbf, TT * DM / 4);

  k_tr_cvt<<<dim3(DFF / 32, DM / 32, NE), dim3(256), 0, stream>>>(w1, w1t, DM, DFF);
  k_tr_cvt<<<dim3(DFF / 32, DM / 32, NE), dim3(256), 0, stream>>>(w3, w3t, DM, DFF);
  k_tr_cvt<<<dim3(DM / 32, DFF / 32, NE), dim3(256), 0, stream>>>(w2, w2t, DFF, DM);
  k_tr_cvt<<<dim3(DFS / 32, DM / 32, 1), dim3(256), 0, stream>>>(ws1, ws1t, DM, DFS);
  k_tr_cvt<<<dim3(DFS / 32, DM / 32, 1), dim3(256), 0, stream>>>(ws3, ws3t, DM, DFS);
  k_tr_cvt<<<dim3(DM / 32, DFS / 32, 1), dim3(256), 0, stream>>>(ws2, ws2t, DFS, DM);

  k_router<<<dim3(TT / 16), dim3(256), 0, stream>>>(x, Wg, counts, tok_slot, wgt_slot);

  // shared up: [TT,DM] x (ws1,ws3) -> silu-mul -> hs [TT,DFS]
  k_gemm<0><<<dim3(DFS / 128, TT / 128, 1), dim3(256), 0, stream>>>(
      hbf, ws1t, ws3t, hs, nullptr, nullptr, nullptr, nullptr, TT, DFS, DM);
  // shared down: hs x ws2 -> out (dense fp32 write, establishes base)
  k_gemm<2><<<dim3(DM / 128, TT / 128, 1), dim3(256), 0, stream>>>(
      hs, ws2t, nullptr, nullptr, out, nullptr, nullptr, nullptr, TT, DM, DFS);
  // routed up: gathered hidden x (w1,w3)[e] -> silu-mul -> hexp
  k_gemm<1><<<dim3(DFF / 128, CAP / 128, NE), dim3(256), 0, stream>>>(
      hbf, w1t, w3t, hexp, nullptr, counts, tok_slot, nullptr, CAP, DFF, DM);
  // routed down: hexp x w2[e] -> weighted atomic scatter into out
  k_gemm<3><<<dim3(DM / 128, CAP / 128, NE), dim3(256), 0, stream>>>(
      hexp, w2t, nullptr, nullptr, out, counts, tok_slot, wgt_slot, CAP, DM, DFF);
}

// Round 2
// 414.131 us; speedup vs baseline: 1.0612x; 1.0612x over previous
//
#include <hip/hip_runtime.h>
#include <stdint.h>

#define TT 4096      // tokens
#define DM 1024      // d_model
#define NE 16        // experts
#define DFF 512      // per-expert ffn
#define DFS 1024     // shared ffn
#define CAP 1024     // capacity

typedef unsigned short u16;
typedef __bf16 bf16x8 __attribute__((ext_vector_type(8)));
typedef float f32x4 __attribute__((ext_vector_type(4)));

typedef __attribute__((address_space(1))) void as1_void;
typedef __attribute__((address_space(3))) void as3_void;

__device__ __forceinline__ u16 f2bf(float f) {
  union { float f; uint32_t u; } v; v.f = f;
  uint32_t u = v.u;
  u += 0x7fffu + ((u >> 16) & 1u);   // RNE
  return (u16)(u >> 16);
}

__device__ __forceinline__ void gl2lds16(const void* g, void* l) {
  __builtin_amdgcn_global_load_lds(
      (as1_void*)(uintptr_t)g,
      (as3_void*)(uint32_t)(uintptr_t)l,
      16, 0, 0);
}

// ---------------- fp32 -> bf16 flat convert ----------------
__global__ __launch_bounds__(256) void k_cvt_bf16(const float4* __restrict__ in,
                                                  ushort4* __restrict__ out, int n4) {
  int i = blockIdx.x * 256 + threadIdx.x;
  if (i >= n4) return;
  float4 v = in[i];
  ushort4 o;
  o.x = f2bf(v.x); o.y = f2bf(v.y); o.z = f2bf(v.z); o.w = f2bf(v.w);
  out[i] = o;
}

// ---------------- all weight transpose-converts in ONE dispatch ----------------
// z decode: [0,16) w1 expert | [16,32) w3 | [32,48) w2 | 48 ws1 | 49 ws3 | 50 ws2
__global__ __launch_bounds__(256) void k_tr_all(
    const float* __restrict__ w1, const float* __restrict__ w3,
    const float* __restrict__ w2, const float* __restrict__ ws1,
    const float* __restrict__ ws3, const float* __restrict__ ws2,
    u16* __restrict__ w1t, u16* __restrict__ w3t, u16* __restrict__ w2t,
    u16* __restrict__ ws1t, u16* __restrict__ ws3t, u16* __restrict__ ws2t) {
  int z = blockIdx.z;
  const float* ip; u16* op; int R, C;
  if (z < 16)      { ip = w1 + (size_t)z * DM * DFF;       op = w1t + (size_t)z * DM * DFF;       R = DM;  C = DFF; }
  else if (z < 32) { int e = z - 16; ip = w3 + (size_t)e * DM * DFF; op = w3t + (size_t)e * DM * DFF; R = DM;  C = DFF; }
  else if (z < 48) { int e = z - 32; ip = w2 + (size_t)e * DFF * DM; op = w2t + (size_t)e * DFF * DM; R = DFF; C = DM; }
  else if (z == 48){ ip = ws1; op = ws1t; R = DM;  C = DFS; }
  else if (z == 49){ ip = ws3; op = ws3t; R = DM;  C = DFS; }
  else             { ip = ws2; op = ws2t; R = DFS; C = DM; }

  int c0 = blockIdx.x * 32, r0 = blockIdx.y * 32;
  if (c0 >= C || r0 >= R) return;   // block-uniform

  __shared__ float tile[32][33];
  int tx = threadIdx.x & 31, ty = threadIdx.x >> 5;   // 32x8
#pragma unroll
  for (int j = 0; j < 4; ++j)
    tile[ty + 8 * j][tx] = ip[(size_t)(r0 + ty + 8 * j) * C + (c0 + tx)];
  __syncthreads();
#pragma unroll
  for (int j = 0; j < 4; ++j)
    op[(size_t)(c0 + ty + 8 * j) * R + (r0 + tx)] = f2bf(tile[tx][ty + 8 * j]);
}

// ---------------- router: fp32 logits, top-2, slot assignment ----------------
__global__ __launch_bounds__(256) void k_router(const float* __restrict__ x,
                                                const float* __restrict__ Wg,
                                                int* __restrict__ counts,
                                                int* __restrict__ tok_slot,
                                                float* __restrict__ wgt_slot) {
  __shared__ float lg[16][17];
  int e = threadIdx.x & 15, tl = threadIdx.x >> 4;
  int t = blockIdx.x * 16 + tl;
  const float* xr = x + (size_t)t * DM;
  float acc = 0.f;
  for (int d = 0; d < DM; d += 4) {
    float4 xv = *(const float4*)(xr + d);
    acc += xv.x * Wg[(d    ) * NE + e];
    acc += xv.y * Wg[(d + 1) * NE + e];
    acc += xv.z * Wg[(d + 2) * NE + e];
    acc += xv.w * Wg[(d + 3) * NE + e];
  }
  lg[tl][e] = acc;
  __syncthreads();
  if (e == 0) {
    float b0 = -1e30f; int i0 = 0;
#pragma unroll
    for (int i = 0; i < NE; ++i) { float v = lg[tl][i]; if (v > b0) { b0 = v; i0 = i; } }
    float b1 = -1e30f; int i1 = 0;
#pragma unroll
    for (int i = 0; i < NE; ++i) { if (i == i0) continue; float v = lg[tl][i]; if (v > b1) { b1 = v; i1 = i; } }
    float ex = __expf(b1 - b0);
    float w0 = 1.f / (1.f + ex);
    float w1 = 1.f - w0;
    int p0 = atomicAdd(&counts[i0], 1);
    if (p0 < CAP) { int s = i0 * CAP + p0; tok_slot[s] = t; wgt_slot[s] = w0; }
    int p1 = atomicAdd(&counts[i1], 1);
    if (p1 < CAP) { int s = i1 * CAP + p1; tok_slot[s] = t; wgt_slot[s] = w1; }
  }
}

// ---------------- merged UP: shared-up (bid<256) + routed-up (bid>=256) ----------------
// dual-B 128x128x(BK=32) bf16 MFMA, K = DM = 1024, epilogue silu(a1)*a3 -> bf16
__global__ __launch_bounds__(256) void k_up(
    const u16* __restrict__ hbf,
    const u16* __restrict__ ws1t, const u16* __restrict__ ws3t,
    const u16* __restrict__ w1t, const u16* __restrict__ w3t,
    u16* __restrict__ hs, u16* __restrict__ hexp,
    const int* __restrict__ counts, const int* __restrict__ tok_slot) {
  const int bid = blockIdx.x;
  const int tid = threadIdx.x;
  const u16* B1p; const u16* B3p; u16* Cp;
  int m0, n0, N;
  int e = -1, cnt = 0;
  if (bid < 256) {
    n0 = (bid & 7) * 128; m0 = (bid >> 3) * 128;
    B1p = ws1t; B3p = ws3t; Cp = hs; N = DFS;
  } else {
    int r = bid - 256;                 // 512 routed blocks: e * (4 n-tiles x 8 m-tiles)
    e = r >> 5; int q = r & 31;
    n0 = (q & 3) * 128; m0 = (q >> 2) * 128;
    cnt = counts[e]; if (cnt > CAP) cnt = CAP;
    if (m0 >= cnt) return;             // uniform exit before any barrier
    B1p = w1t + (size_t)e * (DFF * DM);
    B3p = w3t + (size_t)e * (DFF * DM);
    Cp = hexp + (size_t)e * (CAP * DFF);
    N = DFF;
  }

  __shared__ u16 As[128 * 32];
  __shared__ u16 Bs1[128 * 32];
  __shared__ u16 Bs3[128 * 32];

  const int srow = tid >> 2;
  const int kc = (tid & 3) * 8;
  size_t aoff0, aoff1;
  if (e >= 0) {
    int r0 = m0 + srow, r1 = r0 + 64;
    int t0 = (r0 < cnt) ? tok_slot[e * CAP + r0] : 0;
    int t1 = (r1 < cnt) ? tok_slot[e * CAP + r1] : 0;
    aoff0 = (size_t)t0 * DM + kc;
    aoff1 = (size_t)t1 * DM + kc;
  } else {
    aoff0 = (size_t)(m0 + srow) * DM + kc;
    aoff1 = aoff0 + (size_t)64 * DM;
  }
  const size_t boff0 = (size_t)(n0 + srow) * DM + kc;
  const size_t boff1 = boff0 + (size_t)64 * DM;

  const int lane = tid & 63;
  const int wv = tid >> 6;
  const int wr = (wv >> 1) * 64;
  const int wc = (wv & 1) * 64;
  const int lr = lane & 15;
  const int lq = lane >> 4;

  f32x4 acc1[4][4], acc3[4][4];
#pragma unroll
  for (int i = 0; i < 4; ++i)
#pragma unroll
    for (int j = 0; j < 4; ++j) {
      acc1[i][j] = (f32x4){0.f, 0.f, 0.f, 0.f};
      acc3[i][j] = (f32x4){0.f, 0.f, 0.f, 0.f};
    }

  for (int k0 = 0; k0 < DM; k0 += 32) {
    __syncthreads();
    gl2lds16(hbf + aoff0 + k0, &As[(size_t)tid * 8]);
    gl2lds16(hbf + aoff1 + k0, &As[(size_t)(tid + 256) * 8]);
    gl2lds16(B1p + boff0 + k0, &Bs1[(size_t)tid * 8]);
    gl2lds16(B1p + boff1 + k0, &Bs1[(size_t)(tid + 256) * 8]);
    gl2lds16(B3p + boff0 + k0, &Bs3[(size_t)tid * 8]);
    gl2lds16(B3p + boff1 + k0, &Bs3[(size_t)(tid + 256) * 8]);
    __syncthreads();
    bf16x8 af[4], bf1[4], bf3[4];
#pragma unroll
    for (int i = 0; i < 4; ++i)
      af[i] = *(const bf16x8*)&As[(wr + i * 16 + lr) * 32 + lq * 8];
#pragma unroll
    for (int j = 0; j < 4; ++j) {
      bf1[j] = *(const bf16x8*)&Bs1[(wc + j * 16 + lr) * 32 + lq * 8];
      bf3[j] = *(const bf16x8*)&Bs3[(wc + j * 16 + lr) * 32 + lq * 8];
    }
#pragma unroll
    for (int i = 0; i < 4; ++i)
#pragma unroll
      for (int j = 0; j < 4; ++j) {
        acc1[i][j] = __builtin_amdgcn_mfma_f32_16x16x32_bf16(af[i], bf1[j], acc1[i][j], 0, 0, 0);
        acc3[i][j] = __builtin_amdgcn_mfma_f32_16x16x32_bf16(af[i], bf3[j], acc3[i][j], 0, 0, 0);
      }
  }

#pragma unroll
  for (int i = 0; i < 4; ++i)
#pragma unroll
    for (int r = 0; r < 4; ++r) {
      int row = m0 + wr + i * 16 + lq * 4 + r;
      u16* crow = Cp + (size_t)row * N;
#pragma unroll
      for (int j = 0; j < 4; ++j) {
        float v1 = acc1[i][j][r];
        float v3 = acc3[i][j][r];
        float h = (v1 / (1.f + __expf(-v1))) * v3;   // silu(v1)*v3
        crow[n0 + wc + j * 16 + lr] = f2bf(h);
      }
    }
}

// ---------------- merged DOWN: shared-down (bid<256) + routed-down ----------------
// single-B 128x128 tiles; out zero-initialized; ALL contributions via atomicAdd
__global__ __launch_bounds__(256) void k_down(
    const u16* __restrict__ hs, const u16* __restrict__ ws2t,
    const u16* __restrict__ hexp, const u16* __restrict__ w2t,
    float* __restrict__ out,
    const int* __restrict__ counts, const int* __restrict__ tok_slot,
    const float* __restrict__ wgt_slot) {
  const int bid = blockIdx.x;
  const int tid = threadIdx.x;
  const u16* Ap; const u16* Bp;
  int m0, n0, K, cnt, e = -1;
  if (bid < 256) {
    n0 = (bid & 7) * 128; m0 = (bid >> 3) * 128;
    Ap = hs; Bp = ws2t; K = DFS; cnt = TT;
  } else {
    int r = bid - 256;                 // 1024 routed blocks: e * (8 n-tiles x 8 m-tiles)
    e = r >> 6; int q = r & 63;
    n0 = (q & 7) * 128; m0 = (q >> 3) * 128;
    cnt = counts[e]; if (cnt > CAP) cnt = CAP;
    if (m0 >= cnt) return;
    Ap = hexp + (size_t)e * (CAP * DFF);
    Bp = w2t + (size_t)e * (DM * DFF);
    K = DFF;
  }

  __shared__ u16 As[128 * 32];
  __shared__ u16 Bs[128 * 32];

  const int srow = tid >> 2;
  const int kc = (tid & 3) * 8;
  const size_t aoff0 = (size_t)(m0 + srow) * K + kc;
  const size_t aoff1 = aoff0 + (size_t)64 * K;
  const size_t boff0 = (size_t)(n0 + srow) * K + kc;
  const size_t boff1 = boff0 + (size_t)64 * K;

  const int lane = tid & 63;
  const int wv = tid >> 6;
  const int wr = (wv >> 1) * 64;
  const int wc = (wv & 1) * 64;
  const int lr = lane & 15;
  const int lq = lane >> 4;

  f32x4 acc[4][4];
#pragma unroll
  for (int i = 0; i < 4; ++i)
#pragma unroll
    for (int j = 0; j < 4; ++j) acc[i][j] = (f32x4){0.f, 0.f, 0.f, 0.f};

  for (int k0 = 0; k0 < K; k0 += 32) {
    __syncthreads();
    gl2lds16(Ap + aoff0 + k0, &As[(size_t)tid * 8]);
    gl2lds16(Ap + aoff1 + k0, &As[(size_t)(tid + 256) * 8]);
    gl2lds16(Bp + boff0 + k0, &Bs[(size_t)tid * 8]);
    gl2lds16(Bp + boff1 + k0, &Bs[(size_t)(tid + 256) * 8]);
    __syncthreads();
    bf16x8 af[4], bfr[4];
#pragma unroll
    for (int i = 0; i < 4; ++i)
      af[i] = *(const bf16x8*)&As[(wr + i * 16 + lr) * 32 + lq * 8];
#pragma unroll
    for (int j = 0; j < 4; ++j)
      bfr[j] = *(const bf16x8*)&Bs[(wc + j * 16 + lr) * 32 + lq * 8];
#pragma unroll
    for (int i = 0; i < 4; ++i)
#pragma unroll
      for (int j = 0; j < 4; ++j)
        acc[i][j] = __builtin_amdgcn_mfma_f32_16x16x32_bf16(af[i], bfr[j], acc[i][j], 0, 0, 0);
  }

#pragma unroll
  for (int i = 0; i < 4; ++i)
#pragma unroll
    for (int r = 0; r < 4; ++r) {
      int row = m0 + wr + i * 16 + lq * 4 + r;
      if (row < cnt) {
        int t; float w;
        if (e >= 0) { int s = e * CAP + row; t = tok_slot[s]; w = wgt_slot[s]; }
        else        { t = row; w = 1.f; }
        float* orow = out + (size_t)t * DM;
#pragma unroll
        for (int j = 0; j < 4; ++j)
          atomicAdd(&orow[n0 + wc + j * 16 + lr], w * acc[i][j][r]);
      }
    }
}

// ---------------- host ----------------
extern "C" void kernel_launch(void* const* d_in, const int* in_sizes, int n_in,
                              void* d_out, int out_size, void* d_ws, size_t ws_size,
                              hipStream_t stream) {
  (void)in_sizes; (void)n_in; (void)out_size; (void)ws_size;
  const float* x   = (const float*)d_in[0];
  const float* Wg  = (const float*)d_in[1];
  const float* w1  = (const float*)d_in[2];
  const float* w3  = (const float*)d_in[3];
  const float* w2  = (const float*)d_in[4];
  const float* ws1 = (const float*)d_in[5];
  const float* ws3 = (const float*)d_in[6];
  const float* ws2 = (const float*)d_in[7];
  float* out = (float*)d_out;
  char* ws = (char*)d_ws;

  u16* hbf   = (u16*)(ws + 0);          // 8,388,608 B  [TT,DM] bf16
  u16* w1t   = (u16*)(ws + 8388608);    // 16,777,216 B [E][DFF][DM]
  u16* w3t   = (u16*)(ws + 25165824);   // 16,777,216 B
  u16* w2t   = (u16*)(ws + 41943040);   // 16,777,216 B [E][DM][DFF]
  u16* ws1t  = (u16*)(ws + 58720256);   // 2,097,152 B  [DFS][DM]
  u16* ws3t  = (u16*)(ws + 60817408);   // 2,097,152 B
  u16* ws2t  = (u16*)(ws + 62914560);   // 2,097,152 B  [DM][DFS]
  u16* hs    = (u16*)(ws + 65011712);   // 8,388,608 B  [TT,DFS] bf16
  u16* hexp  = (u16*)(ws + 73400320);   // 16,777,216 B [E][CAP][DFF] bf16
  int* counts    = (int*)(ws + 90177536);
  int* tok_slot  = (int*)(ws + 90177792);
  float* wgt_slot = (float*)(ws + 90243328);

  hipMemsetAsync(counts, 0, NE * sizeof(int), stream);
  hipMemsetAsync(out, 0, (size_t)TT * DM * sizeof(float), stream);

  k_cvt_bf16<<<dim3((TT * DM / 4) / 256), dim3(256), 0, stream>>>(
      (const float4*)x, (ushort4*)hbf, TT * DM / 4);

  k_tr_all<<<dim3(32, 32, 51), dim3(256), 0, stream>>>(
      w1, w3, w2, ws1, ws3, ws2, w1t, w3t, w2t, ws1t, ws3t, ws2t);

  k_router<<<dim3(TT / 16), dim3(256), 0, stream>>>(x, Wg, counts, tok_slot, wgt_slot);

  // merged up: 256 shared tiles + 16*32 routed tiles (early-exit beyond count)
  k_up<<<dim3(256 + NE * 32), dim3(256), 0, stream>>>(
      hbf, ws1t, ws3t, w1t, w3t, hs, hexp, counts, tok_slot);

  // merged down: 256 shared tiles + 16*64 routed tiles, all atomicAdd onto zeroed out
  k_down<<<dim3(256 + NE * 64), dim3(256), 0, stream>>>(
      hs, ws2t, hexp, w2t, out, counts, tok_slot, wgt_slot);
}

// Round 3
// 392.013 us; speedup vs baseline: 1.1211x; 1.0564x over previous
//
#include <hip/hip_runtime.h>
#include <stdint.h>

#define TT 4096      // tokens
#define DM 1024      // d_model
#define NE 16        // experts
#define DFF 512      // per-expert ffn
#define DFS 1024     // shared ffn
#define CAP 1024     // capacity

typedef unsigned short u16;
typedef __bf16 bf16x8 __attribute__((ext_vector_type(8)));
typedef float f32x4 __attribute__((ext_vector_type(4)));

typedef __attribute__((address_space(1))) void as1_void;
typedef __attribute__((address_space(3))) void as3_void;

__device__ __forceinline__ u16 f2bf(float f) {
  union { float f; uint32_t u; } v; v.f = f;
  uint32_t u = v.u;
  u += 0x7fffu + ((u >> 16) & 1u);   // RNE
  return (u16)(u >> 16);
}

__device__ __forceinline__ void gl2lds16(const void* g, void* l) {
  __builtin_amdgcn_global_load_lds(
      (as1_void*)(uintptr_t)g,
      (as3_void*)(uint32_t)(uintptr_t)l,
      16, 0, 0);
}

// ---------------- all weight transpose-converts in ONE dispatch ----------------
// fp32 [R,C] -> bf16 [C,R].  64x64 tiles, float4 loads, ushort4 stores.
// z decode: [0,16) w1 | [16,32) w3 | [32,48) w2 | 48 ws1 | 49 ws3 | 50 ws2
__global__ __launch_bounds__(256) void k_tr_all(
    const float* __restrict__ w1, const float* __restrict__ w3,
    const float* __restrict__ w2, const float* __restrict__ ws1,
    const float* __restrict__ ws3, const float* __restrict__ ws2,
    u16* __restrict__ w1t, u16* __restrict__ w3t, u16* __restrict__ w2t,
    u16* __restrict__ ws1t, u16* __restrict__ ws3t, u16* __restrict__ ws2t) {
  int z = blockIdx.z;
  const float* ip; u16* op; int R, C;
  if (z < 16)      { ip = w1 + (size_t)z * DM * DFF;       op = w1t + (size_t)z * DM * DFF;       R = DM;  C = DFF; }
  else if (z < 32) { int e = z - 16; ip = w3 + (size_t)e * DM * DFF; op = w3t + (size_t)e * DM * DFF; R = DM;  C = DFF; }
  else if (z < 48) { int e = z - 32; ip = w2 + (size_t)e * DFF * DM; op = w2t + (size_t)e * DFF * DM; R = DFF; C = DM; }
  else if (z == 48){ ip = ws1; op = ws1t; R = DM;  C = DFS; }
  else if (z == 49){ ip = ws3; op = ws3t; R = DM;  C = DFS; }
  else             { ip = ws2; op = ws2t; R = DFS; C = DM; }

  int c0 = blockIdx.x * 64, r0 = blockIdx.y * 64;
  if (c0 >= C || r0 >= R) return;   // block-uniform

  __shared__ float tile[64][68];    // row stride 272B: 16B-aligned, bank-friendly
  int tx = threadIdx.x & 15, ty = threadIdx.x >> 4;
#pragma unroll
  for (int j = 0; j < 4; ++j) {
    int r = ty + 16 * j;
    float4 v = *(const float4*)&ip[(size_t)(r0 + r) * C + c0 + tx * 4];
    *(float4*)&tile[r][tx * 4] = v;
  }
  __syncthreads();
#pragma unroll
  for (int j = 0; j < 4; ++j) {
    int c = ty + 16 * j;
    ushort4 o;
    o.x = f2bf(tile[tx * 4 + 0][c]);
    o.y = f2bf(tile[tx * 4 + 1][c]);
    o.z = f2bf(tile[tx * 4 + 2][c]);
    o.w = f2bf(tile[tx * 4 + 3][c]);
    *(ushort4*)&op[(size_t)(c0 + c) * R + r0 + tx * 4] = o;
  }
}

// ---------------- router + hidden bf16 convert, fused ----------------
// 16 tokens/block; 16 k-split threads per token (coalesced x reads, read-once).
__global__ __launch_bounds__(256) void k_router(const float* __restrict__ x,
                                                const float* __restrict__ Wg,
                                                u16* __restrict__ hbf,
                                                int* __restrict__ counts,
                                                int* __restrict__ tok_slot,
                                                float* __restrict__ wgt_slot) {
  __shared__ float red[16][16][17];   // [token][kpart][expert]
  __shared__ float lg[16][17];
  int tid = threadIdx.x;
  int tl = tid >> 4, kp = tid & 15;
  int t = blockIdx.x * 16 + tl;
  const float* xr = x + (size_t)t * DM + kp * 64;
  u16* hr = hbf + (size_t)t * DM + kp * 64;
  float acc[16];
#pragma unroll
  for (int e = 0; e < 16; ++e) acc[e] = 0.f;
#pragma unroll 4
  for (int i = 0; i < 16; ++i) {
    float4 xv = *(const float4*)(xr + i * 4);
    ushort4 o;
    o.x = f2bf(xv.x); o.y = f2bf(xv.y); o.z = f2bf(xv.z); o.w = f2bf(xv.w);
    *(ushort4*)(hr + i * 4) = o;
    const float* wgr = Wg + (size_t)(kp * 64 + i * 4) * NE;
#pragma unroll
    for (int q = 0; q < 4; ++q) {
      float xq = (q == 0) ? xv.x : (q == 1) ? xv.y : (q == 2) ? xv.z : xv.w;
      float4 a = *(const float4*)(wgr + q * NE);
      float4 b = *(const float4*)(wgr + q * NE + 4);
      float4 c = *(const float4*)(wgr + q * NE + 8);
      float4 d = *(const float4*)(wgr + q * NE + 12);
      acc[0] += xq * a.x;  acc[1] += xq * a.y;  acc[2] += xq * a.z;  acc[3] += xq * a.w;
      acc[4] += xq * b.x;  acc[5] += xq * b.y;  acc[6] += xq * b.z;  acc[7] += xq * b.w;
      acc[8] += xq * c.x;  acc[9] += xq * c.y;  acc[10] += xq * c.z; acc[11] += xq * c.w;
      acc[12] += xq * d.x; acc[13] += xq * d.y; acc[14] += xq * d.z; acc[15] += xq * d.w;
    }
  }
#pragma unroll
  for (int e = 0; e < 16; ++e) red[tl][kp][e] = acc[e];
  __syncthreads();
  // thread (tl, e=kp) reduces expert kp over the 16 k-parts
  float logit = 0.f;
#pragma unroll
  for (int p = 0; p < 16; ++p) logit += red[tl][p][kp];
  lg[tl][kp] = logit;
  __syncthreads();
  if (kp == 0) {
    float b0 = -1e30f; int i0 = 0;
#pragma unroll
    for (int i = 0; i < NE; ++i) { float v = lg[tl][i]; if (v > b0) { b0 = v; i0 = i; } }
    float b1 = -1e30f; int i1 = 0;
#pragma unroll
    for (int i = 0; i < NE; ++i) { if (i == i0) continue; float v = lg[tl][i]; if (v > b1) { b1 = v; i1 = i; } }
    float ex = __expf(b1 - b0);
    float w0 = 1.f / (1.f + ex);
    float w1 = 1.f - w0;
    int p0 = atomicAdd(&counts[i0], 1);
    if (p0 < CAP) { int s = i0 * CAP + p0; tok_slot[s] = t; wgt_slot[s] = w0; }
    int p1 = atomicAdd(&counts[i1], 1);
    if (p1 < CAP) { int s = i1 * CAP + p1; tok_slot[s] = t; wgt_slot[s] = w1; }
  }
}

// LDS tile: 128 rows x 64 k (u16), row = 128B = 8 chunks of 16B.
// Chunk c of row r lives in slot (c ^ (r&7))  -> conflict-free b128 fragment reads.
#define FRAG(BUF, ROW, CC)                                                       \
  (*(const bf16x8*)&BUF[(ROW) * 64 + ((((CC) * 4 + lq) ^ ((ROW) & 7)) << 3)])

// ---------------- merged UP: shared-up (bid<256) + routed-up ----------------
// dual-B 128x128, BK=64, 16x16x32 bf16 MFMA, epilogue silu(a1)*a3 -> bf16
__global__ __launch_bounds__(256) void k_up(
    const u16* __restrict__ hbf,
    const u16* __restrict__ ws1t, const u16* __restrict__ ws3t,
    const u16* __restrict__ w1t, const u16* __restrict__ w3t,
    u16* __restrict__ hs, u16* __restrict__ hexp,
    const int* __restrict__ counts, const int* __restrict__ tok_slot) {
  const int bid = blockIdx.x;
  const int tid = threadIdx.x;
  const u16* B1p; const u16* B3p; u16* Cp;
  int m0, n0, N;
  int e = -1, cnt = 0;
  if (bid < 256) {
    n0 = (bid & 7) * 128; m0 = (bid >> 3) * 128;
    B1p = ws1t; B3p = ws3t; Cp = hs; N = DFS;
  } else {
    int r = bid - 256;                 // 512 routed blocks: e * (4 n-tiles x 8 m-tiles)
    e = r >> 5; int q = r & 31;
    n0 = (q & 3) * 128; m0 = (q >> 2) * 128;
    cnt = counts[e]; if (cnt > CAP) cnt = CAP;
    if (m0 >= cnt) return;             // uniform exit before any barrier
    B1p = w1t + (size_t)e * (DFF * DM);
    B3p = w3t + (size_t)e * (DFF * DM);
    Cp = hexp + (size_t)e * (CAP * DFF);
    N = DFF;
  }

  __shared__ __align__(16) u16 As[128 * 64];
  __shared__ __align__(16) u16 Bs1[128 * 64];
  __shared__ __align__(16) u16 Bs3[128 * 64];

  // staging: instruction j moves 16B chunk; LDS dest = (tid + 256j)*16B (wave-contiguous)
  size_t aoff[4], boff[4];
#pragma unroll
  for (int j = 0; j < 4; ++j) {
    int L = tid + 256 * j;
    int row = L >> 3, slot = L & 7;
    int c = slot ^ (row & 7);
    if (e >= 0) {
      int gr = m0 + row;
      int tk = (gr < cnt) ? tok_slot[e * CAP + gr] : 0;
      aoff[j] = (size_t)tk * DM + c * 8;
    } else {
      aoff[j] = (size_t)(m0 + row) * DM + c * 8;
    }
    boff[j] = (size_t)(n0 + row) * DM + c * 8;
  }

  const int lane = tid & 63;
  const int wv = tid >> 6;
  const int wr = (wv >> 1) * 64;
  const int wc = (wv & 1) * 64;
  const int lr = lane & 15;
  const int lq = lane >> 4;

  f32x4 acc1[4][4], acc3[4][4];
#pragma unroll
  for (int i = 0; i < 4; ++i)
#pragma unroll
    for (int j = 0; j < 4; ++j) {
      acc1[i][j] = (f32x4){0.f, 0.f, 0.f, 0.f};
      acc3[i][j] = (f32x4){0.f, 0.f, 0.f, 0.f};
    }

  for (int k0 = 0; k0 < DM; k0 += 64) {
    __syncthreads();
#pragma unroll
    for (int j = 0; j < 4; ++j) gl2lds16(hbf + aoff[j] + k0, &As[(size_t)(tid + 256 * j) * 8]);
#pragma unroll
    for (int j = 0; j < 4; ++j) gl2lds16(B1p + boff[j] + k0, &Bs1[(size_t)(tid + 256 * j) * 8]);
#pragma unroll
    for (int j = 0; j < 4; ++j) gl2lds16(B3p + boff[j] + k0, &Bs3[(size_t)(tid + 256 * j) * 8]);
    __syncthreads();
#pragma unroll
    for (int cc = 0; cc < 2; ++cc) {
      bf16x8 af[4], bf1[4], bf3[4];
#pragma unroll
      for (int i = 0; i < 4; ++i) af[i] = FRAG(As, wr + i * 16 + lr, cc);
#pragma unroll
      for (int j = 0; j < 4; ++j) {
        bf1[j] = FRAG(Bs1, wc + j * 16 + lr, cc);
        bf3[j] = FRAG(Bs3, wc + j * 16 + lr, cc);
      }
#pragma unroll
      for (int i = 0; i < 4; ++i)
#pragma unroll
        for (int j = 0; j < 4; ++j) {
          acc1[i][j] = __builtin_amdgcn_mfma_f32_16x16x32_bf16(af[i], bf1[j], acc1[i][j], 0, 0, 0);
          acc3[i][j] = __builtin_amdgcn_mfma_f32_16x16x32_bf16(af[i], bf3[j], acc3[i][j], 0, 0, 0);
        }
    }
  }

#pragma unroll
  for (int i = 0; i < 4; ++i)
#pragma unroll
    for (int r = 0; r < 4; ++r) {
      int row = m0 + wr + i * 16 + lq * 4 + r;
      u16* crow = Cp + (size_t)row * N;
#pragma unroll
      for (int j = 0; j < 4; ++j) {
        float v1 = acc1[i][j][r];
        float v3 = acc3[i][j][r];
        float h = (v1 / (1.f + __expf(-v1))) * v3;   // silu(v1)*v3
        crow[n0 + wc + j * 16 + lr] = f2bf(h);
      }
    }
}

// ---------------- merged DOWN: shared-down (bid<256) + routed-down ----------------
// single-B 128x128, BK=64; out zeroed; ALL contributions via atomicAdd
__global__ __launch_bounds__(256, 4) void k_down(
    const u16* __restrict__ hs, const u16* __restrict__ ws2t,
    const u16* __restrict__ hexp, const u16* __restrict__ w2t,
    float* __restrict__ out,
    const int* __restrict__ counts, const int* __restrict__ tok_slot,
    const float* __restrict__ wgt_slot) {
  const int bid = blockIdx.x;
  const int tid = threadIdx.x;
  const u16* Ap; const u16* Bp;
  int m0, n0, K, cnt, e = -1;
  if (bid < 256) {
    n0 = (bid & 7) * 128; m0 = (bid >> 3) * 128;
    Ap = hs; Bp = ws2t; K = DFS; cnt = TT;
  } else {
    int r = bid - 256;                 // 1024 routed blocks: e * (8 n-tiles x 8 m-tiles)
    e = r >> 6; int q = r & 63;
    n0 = (q & 7) * 128; m0 = (q >> 3) * 128;
    cnt = counts[e]; if (cnt > CAP) cnt = CAP;
    if (m0 >= cnt) return;
    Ap = hexp + (size_t)e * (CAP * DFF);
    Bp = w2t + (size_t)e * (DM * DFF);
    K = DFF;
  }

  __shared__ __align__(16) u16 As[128 * 64];
  __shared__ __align__(16) u16 Bs[128 * 64];

  size_t aoff[4], boff[4];
#pragma unroll
  for (int j = 0; j < 4; ++j) {
    int L = tid + 256 * j;
    int row = L >> 3, slot = L & 7;
    int c = slot ^ (row & 7);
    aoff[j] = (size_t)(m0 + row) * K + c * 8;
    boff[j] = (size_t)(n0 + row) * K + c * 8;
  }

  const int lane = tid & 63;
  const int wv = tid >> 6;
  const int wr = (wv >> 1) * 64;
  const int wc = (wv & 1) * 64;
  const int lr = lane & 15;
  const int lq = lane >> 4;

  f32x4 acc[4][4];
#pragma unroll
  for (int i = 0; i < 4; ++i)
#pragma unroll
    for (int j = 0; j < 4; ++j) acc[i][j] = (f32x4){0.f, 0.f, 0.f, 0.f};

  for (int k0 = 0; k0 < K; k0 += 64) {
    __syncthreads();
#pragma unroll
    for (int j = 0; j < 4; ++j) gl2lds16(Ap + aoff[j] + k0, &As[(size_t)(tid + 256 * j) * 8]);
#pragma unroll
    for (int j = 0; j < 4; ++j) gl2lds16(Bp + boff[j] + k0, &Bs[(size_t)(tid + 256 * j) * 8]);
    __syncthreads();
#pragma unroll
    for (int cc = 0; cc < 2; ++cc) {
      bf16x8 af[4], bfr[4];
#pragma unroll
      for (int i = 0; i < 4; ++i) af[i] = FRAG(As, wr + i * 16 + lr, cc);
#pragma unroll
      for (int j = 0; j < 4; ++j) bfr[j] = FRAG(Bs, wc + j * 16 + lr, cc);
#pragma unroll
      for (int i = 0; i < 4; ++i)
#pragma unroll
        for (int j = 0; j < 4; ++j)
          acc[i][j] = __builtin_amdgcn_mfma_f32_16x16x32_bf16(af[i], bfr[j], acc[i][j], 0, 0, 0);
    }
  }

#pragma unroll
  for (int i = 0; i < 4; ++i)
#pragma unroll
    for (int r = 0; r < 4; ++r) {
      int row = m0 + wr + i * 16 + lq * 4 + r;
      if (row < cnt) {
        int t; float w;
        if (e >= 0) { int s = e * CAP + row; t = tok_slot[s]; w = wgt_slot[s]; }
        else        { t = row; w = 1.f; }
        float* orow = out + (size_t)t * DM;
#pragma unroll
        for (int j = 0; j < 4; ++j)
          atomicAdd(&orow[n0 + wc + j * 16 + lr], w * acc[i][j][r]);
      }
    }
}

// ---------------- host ----------------
extern "C" void kernel_launch(void* const* d_in, const int* in_sizes, int n_in,
                              void* d_out, int out_size, void* d_ws, size_t ws_size,
                              hipStream_t stream) {
  (void)in_sizes; (void)n_in; (void)out_size; (void)ws_size;
  const float* x   = (const float*)d_in[0];
  const float* Wg  = (const float*)d_in[1];
  const float* w1  = (const float*)d_in[2];
  const float* w3  = (const float*)d_in[3];
  const float* w2  = (const float*)d_in[4];
  const float* ws1 = (const float*)d_in[5];
  const float* ws3 = (const float*)d_in[6];
  const float* ws2 = (const float*)d_in[7];
  float* out = (float*)d_out;
  char* ws = (char*)d_ws;

  u16* hbf   = (u16*)(ws + 0);          // 8,388,608 B  [TT,DM] bf16
  u16* w1t   = (u16*)(ws + 8388608);    // 16,777,216 B [E][DFF][DM]
  u16* w3t   = (u16*)(ws + 25165824);   // 16,777,216 B
  u16* w2t   = (u16*)(ws + 41943040);   // 16,777,216 B [E][DM][DFF]
  u16* ws1t  = (u16*)(ws + 58720256);   // 2,097,152 B  [DFS][DM]
  u16* ws3t  = (u16*)(ws + 60817408);   // 2,097,152 B
  u16* ws2t  = (u16*)(ws + 62914560);   // 2,097,152 B  [DM][DFS]
  u16* hs    = (u16*)(ws + 65011712);   // 8,388,608 B  [TT,DFS] bf16
  u16* hexp  = (u16*)(ws + 73400320);   // 16,777,216 B [E][CAP][DFF] bf16
  int* counts    = (int*)(ws + 90177536);
  int* tok_slot  = (int*)(ws + 90177792);
  float* wgt_slot = (float*)(ws + 90243328);

  hipMemsetAsync(counts, 0, NE * sizeof(int), stream);
  hipMemsetAsync(out, 0, (size_t)TT * DM * sizeof(float), stream);

  k_tr_all<<<dim3(16, 16, 51), dim3(256), 0, stream>>>(
      w1, w3, w2, ws1, ws3, ws2, w1t, w3t, w2t, ws1t, ws3t, ws2t);

  k_router<<<dim3(TT / 16), dim3(256), 0, stream>>>(x, Wg, hbf, counts, tok_slot, wgt_slot);

  // merged up: 256 shared tiles + 16*32 routed tiles (early-exit beyond count)
  k_up<<<dim3(256 + NE * 32), dim3(256), 0, stream>>>(
      hbf, ws1t, ws3t, w1t, w3t, hs, hexp, counts, tok_slot);

  // merged down: 256 shared tiles + 16*64 routed tiles, all atomicAdd onto zeroed out
  k_down<<<dim3(256 + NE * 64), dim3(256), 0, stream>>>(
      hs, ws2t, hexp, w2t, out, counts, tok_slot, wgt_slot);
}

// Round 4
// 335.586 us; speedup vs baseline: 1.3095x; 1.1681x over previous
//
#include <hip/hip_runtime.h>
#include <stdint.h>

#define TT 4096      // tokens
#define DM 1024      // d_model
#define NE 16        // experts
#define DFF 512      // per-expert ffn
#define DFS 1024     // shared ffn
#define CAP 1024     // capacity

typedef unsigned short u16;
typedef __bf16 bf16x8 __attribute__((ext_vector_type(8)));
typedef float f32x4 __attribute__((ext_vector_type(4)));

typedef __attribute__((address_space(1))) void as1_void;
typedef __attribute__((address_space(3))) void as3_void;

__device__ __forceinline__ u16 f2bf(float f) {
  union { float f; uint32_t u; } v; v.f = f;
  uint32_t u = v.u;
  u += 0x7fffu + ((u >> 16) & 1u);   // RNE
  return (u16)(u >> 16);
}

__device__ __forceinline__ float bf2f(u16 b) {
  union { uint32_t u; float f; } v; v.u = ((uint32_t)b) << 16;
  return v.f;
}

__device__ __forceinline__ void gl2lds16(const void* g, void* l) {
  __builtin_amdgcn_global_load_lds(
      (as1_void*)(uintptr_t)g,
      (as3_void*)(uint32_t)(uintptr_t)l,
      16, 0, 0);
}

// ============ PREP: router (+hidden bf16 cast) and all weight transposes ============
// bid < 256: router block (16 tokens, 16 k-split threads each)
// bid >= 256: transpose block; tb = bid-256, z = tb>>8, xy = tb&255
//   z decode: [0,16) w1 | [16,32) w3 | [32,48) w2 | 48 ws1 | 49 ws3 | 50 ws2
__global__ __launch_bounds__(256) void k_prep(
    const float* __restrict__ x, const float* __restrict__ Wg,
    const float* __restrict__ w1, const float* __restrict__ w3,
    const float* __restrict__ w2, const float* __restrict__ ws1,
    const float* __restrict__ ws3, const float* __restrict__ ws2,
    u16* __restrict__ hbf,
    u16* __restrict__ w1t, u16* __restrict__ w3t, u16* __restrict__ w2t,
    u16* __restrict__ ws1t, u16* __restrict__ ws3t, u16* __restrict__ ws2t,
    int* __restrict__ counts, int* __restrict__ tok_slot,
    int* __restrict__ tslot, float* __restrict__ tw) {
  __shared__ __align__(16) char smraw[18496];
  const int bid = blockIdx.x;
  const int tid = threadIdx.x;

  if (bid < 256) {
    // ---------------- router ----------------
    float (*red)[16][17] = (float(*)[16][17])smraw;           // [token][kpart][expert]
    float (*lg)[17] = (float(*)[17])(smraw + 17408);          // [token][expert]
    int tl = tid >> 4, kp = tid & 15;
    int t = bid * 16 + tl;
    const float* xr = x + (size_t)t * DM + kp * 64;
    u16* hr = hbf + (size_t)t * DM + kp * 64;
    float acc[16];
#pragma unroll
    for (int e = 0; e < 16; ++e) acc[e] = 0.f;
#pragma unroll 4
    for (int i = 0; i < 16; ++i) {
      float4 xv = *(const float4*)(xr + i * 4);
      ushort4 o;
      o.x = f2bf(xv.x); o.y = f2bf(xv.y); o.z = f2bf(xv.z); o.w = f2bf(xv.w);
      *(ushort4*)(hr + i * 4) = o;
      const float* wgr = Wg + (size_t)(kp * 64 + i * 4) * NE;
#pragma unroll
      for (int q = 0; q < 4; ++q) {
        float xq = (q == 0) ? xv.x : (q == 1) ? xv.y : (q == 2) ? xv.z : xv.w;
        float4 a = *(const float4*)(wgr + q * NE);
        float4 b = *(const float4*)(wgr + q * NE + 4);
        float4 c = *(const float4*)(wgr + q * NE + 8);
        float4 d = *(const float4*)(wgr + q * NE + 12);
        acc[0] += xq * a.x;  acc[1] += xq * a.y;  acc[2] += xq * a.z;  acc[3] += xq * a.w;
        acc[4] += xq * b.x;  acc[5] += xq * b.y;  acc[6] += xq * b.z;  acc[7] += xq * b.w;
        acc[8] += xq * c.x;  acc[9] += xq * c.y;  acc[10] += xq * c.z; acc[11] += xq * c.w;
        acc[12] += xq * d.x; acc[13] += xq * d.y; acc[14] += xq * d.z; acc[15] += xq * d.w;
      }
    }
#pragma unroll
    for (int e = 0; e < 16; ++e) red[tl][kp][e] = acc[e];
    __syncthreads();
    float logit = 0.f;
#pragma unroll
    for (int p = 0; p < 16; ++p) logit += red[tl][p][kp];
    lg[tl][kp] = logit;
    __syncthreads();
    if (kp == 0) {
      float b0 = -1e30f; int i0 = 0;
#pragma unroll
      for (int i = 0; i < NE; ++i) { float v = lg[tl][i]; if (v > b0) { b0 = v; i0 = i; } }
      float b1 = -1e30f; int i1 = 0;
#pragma unroll
      for (int i = 0; i < NE; ++i) { if (i == i0) continue; float v = lg[tl][i]; if (v > b1) { b1 = v; i1 = i; } }
      float ex = __expf(b1 - b0);
      float w0 = 1.f / (1.f + ex);
      float w1v = 1.f - w0;
      int p0 = atomicAdd(&counts[i0], 1);
      int s0 = -1;
      if (p0 < CAP) { s0 = i0 * CAP + p0; tok_slot[s0] = t; }
      tslot[2 * t] = s0; tw[2 * t] = w0;
      int p1 = atomicAdd(&counts[i1], 1);
      int s1 = -1;
      if (p1 < CAP) { s1 = i1 * CAP + p1; tok_slot[s1] = t; }
      tslot[2 * t + 1] = s1; tw[2 * t + 1] = w1v;
    }
    return;
  }

  // ---------------- transpose-convert fp32 [R,C] -> bf16 [C,R] ----------------
  int tb = bid - 256;
  int z = tb >> 8, xy = tb & 255;
  const float* ip; u16* op; int R, C;
  if (z < 16)      { ip = w1 + (size_t)z * DM * DFF;       op = w1t + (size_t)z * DM * DFF;       R = DM;  C = DFF; }
  else if (z < 32) { int e = z - 16; ip = w3 + (size_t)e * DM * DFF; op = w3t + (size_t)e * DM * DFF; R = DM;  C = DFF; }
  else if (z < 48) { int e = z - 32; ip = w2 + (size_t)e * DFF * DM; op = w2t + (size_t)e * DFF * DM; R = DFF; C = DM; }
  else if (z == 48){ ip = ws1; op = ws1t; R = DM;  C = DFS; }
  else if (z == 49){ ip = ws3; op = ws3t; R = DM;  C = DFS; }
  else             { ip = ws2; op = ws2t; R = DFS; C = DM; }

  int c0 = (xy & 15) * 64, r0 = (xy >> 4) * 64;
  if (c0 >= C || r0 >= R) return;   // block-uniform

  float (*tile)[68] = (float(*)[68])smraw;   // 64 x 68 fp32
  int tx = tid & 15, ty = tid >> 4;
#pragma unroll
  for (int j = 0; j < 4; ++j) {
    int r = ty + 16 * j;
    float4 v = *(const float4*)&ip[(size_t)(r0 + r) * C + c0 + tx * 4];
    *(float4*)&tile[r][tx * 4] = v;
  }
  __syncthreads();
#pragma unroll
  for (int j = 0; j < 4; ++j) {
    int c = ty + 16 * j;
    ushort4 o;
    o.x = f2bf(tile[tx * 4 + 0][c]);
    o.y = f2bf(tile[tx * 4 + 1][c]);
    o.z = f2bf(tile[tx * 4 + 2][c]);
    o.w = f2bf(tile[tx * 4 + 3][c]);
    *(ushort4*)&op[(size_t)(c0 + c) * R + r0 + tx * 4] = o;
  }
}

// LDS tile rows are 64 u16 = 128B = 8 chunks of 16B; chunk c of row r in slot c^(r&7).
#define FRAG(BUF, ROW, CC)                                                       \
  (*(const bf16x8*)&BUF[(ROW) * 64 + ((((CC) * 4 + lq) ^ ((ROW) & 7)) << 3)])

// ============ UP: 128x64 tile, 2 waves, BK=64, dual-B, silu(a1)*a3 -> bf16 ============
// bid < 512: shared (A=hbf, B=ws1t/ws3t, C=hs, N=DFS)
// bid >= 512: routed (A=gather(hbf), B=w1t/w3t[e], C=hexp[e], N=DFF)
__global__ __launch_bounds__(128) void k_up(
    const u16* __restrict__ hbf,
    const u16* __restrict__ ws1t, const u16* __restrict__ ws3t,
    const u16* __restrict__ w1t, const u16* __restrict__ w3t,
    u16* __restrict__ hs, u16* __restrict__ hexp,
    const int* __restrict__ counts, const int* __restrict__ tok_slot) {
  const int bid = blockIdx.x;
  const int tid = threadIdx.x;
  const u16* B1p; const u16* B3p; u16* Cp;
  int m0, n0, N;
  int e = -1, cnt = 0;
  if (bid < 512) {
    m0 = (bid >> 4) * 128; n0 = (bid & 15) * 64;
    B1p = ws1t; B3p = ws3t; Cp = hs; N = DFS;
  } else {
    int r = bid - 512;                  // 1024 routed: e * (8 m-tiles x 8 n-tiles)
    e = r >> 6; int q = r & 63;
    m0 = (q >> 3) * 128; n0 = (q & 7) * 64;
    cnt = counts[e]; if (cnt > CAP) cnt = CAP;
    if (m0 >= cnt) return;              // uniform exit before any barrier
    B1p = w1t + (size_t)e * (DFF * DM);
    B3p = w3t + (size_t)e * (DFF * DM);
    Cp = hexp + (size_t)e * (CAP * DFF);
    N = DFF;
  }

  __shared__ __align__(16) u16 As[128 * 64];
  __shared__ __align__(16) u16 Bs1[64 * 64];
  __shared__ __align__(16) u16 Bs3[64 * 64];

  uint32_t aoff[8], boff[4];
#pragma unroll
  for (int j = 0; j < 8; ++j) {
    int L = tid + 128 * j;
    int row = L >> 3;
    int c = (L & 7) ^ (row & 7);
    int gr;
    if (e >= 0) {
      int rr = m0 + row;
      gr = (rr < cnt) ? tok_slot[e * CAP + rr] : 0;
    } else {
      gr = m0 + row;
    }
    aoff[j] = (uint32_t)gr * DM + c * 8;
  }
#pragma unroll
  for (int j = 0; j < 4; ++j) {
    int L = tid + 128 * j;
    int row = L >> 3;
    int c = (L & 7) ^ (row & 7);
    boff[j] = (uint32_t)(n0 + row) * DM + c * 8;
  }

  const int lane = tid & 63;
  const int wv = tid >> 6;
  const int wr = wv * 64;
  const int lr = lane & 15;
  const int lq = lane >> 4;

  f32x4 acc1[4][4], acc3[4][4];
#pragma unroll
  for (int i = 0; i < 4; ++i)
#pragma unroll
    for (int j = 0; j < 4; ++j) {
      acc1[i][j] = (f32x4){0.f, 0.f, 0.f, 0.f};
      acc3[i][j] = (f32x4){0.f, 0.f, 0.f, 0.f};
    }

  for (int k0 = 0; k0 < DM; k0 += 64) {
    __syncthreads();
#pragma unroll
    for (int j = 0; j < 8; ++j) gl2lds16(hbf + aoff[j] + k0, &As[(size_t)(tid + 128 * j) * 8]);
#pragma unroll
    for (int j = 0; j < 4; ++j) gl2lds16(B1p + boff[j] + k0, &Bs1[(size_t)(tid + 128 * j) * 8]);
#pragma unroll
    for (int j = 0; j < 4; ++j) gl2lds16(B3p + boff[j] + k0, &Bs3[(size_t)(tid + 128 * j) * 8]);
    __syncthreads();
#pragma unroll
    for (int cc = 0; cc < 2; ++cc) {
      bf16x8 af[4], bf1[4], bf3[4];
#pragma unroll
      for (int i = 0; i < 4; ++i) af[i] = FRAG(As, wr + i * 16 + lr, cc);
#pragma unroll
      for (int j = 0; j < 4; ++j) {
        bf1[j] = FRAG(Bs1, j * 16 + lr, cc);
        bf3[j] = FRAG(Bs3, j * 16 + lr, cc);
      }
#pragma unroll
      for (int i = 0; i < 4; ++i)
#pragma unroll
        for (int j = 0; j < 4; ++j) {
          acc1[i][j] = __builtin_amdgcn_mfma_f32_16x16x32_bf16(af[i], bf1[j], acc1[i][j], 0, 0, 0);
          acc3[i][j] = __builtin_amdgcn_mfma_f32_16x16x32_bf16(af[i], bf3[j], acc3[i][j], 0, 0, 0);
        }
    }
  }

#pragma unroll
  for (int i = 0; i < 4; ++i)
#pragma unroll
    for (int r = 0; r < 4; ++r) {
      int row = m0 + wr + i * 16 + lq * 4 + r;
      u16* crow = Cp + (size_t)row * N;
#pragma unroll
      for (int j = 0; j < 4; ++j) {
        float v1 = acc1[i][j][r];
        float v3 = acc3[i][j][r];
        float h = (v1 / (1.f + __expf(-v1))) * v3;   // silu(v1)*v3
        crow[n0 + j * 16 + lr] = f2bf(h);
      }
    }
}

// ============ DOWN: 128x64 tile, 2 waves, BK=64, single-B, ALL PLAIN STORES ============
// bid < 512: shared (A=hs, B=ws2t, K=DFS) -> out fp32 (covers every element)
// bid >= 512: routed (A=hexp[e], B=w2t[e], K=DFF) -> ob bf16 per-slot rows
__global__ __launch_bounds__(128) void k_down(
    const u16* __restrict__ hs, const u16* __restrict__ ws2t,
    const u16* __restrict__ hexp, const u16* __restrict__ w2t,
    float* __restrict__ out, u16* __restrict__ ob,
    const int* __restrict__ counts) {
  const int bid = blockIdx.x;
  const int tid = threadIdx.x;
  const u16* Ap; const u16* Bp;
  int m0, n0, K, e = -1;
  if (bid < 512) {
    m0 = (bid >> 4) * 128; n0 = (bid & 15) * 64;
    Ap = hs; Bp = ws2t; K = DFS;
  } else {
    int r = bid - 512;                  // 2048 routed: e * (8 m-tiles x 16 n-tiles)
    e = r >> 7; int q = r & 127;
    m0 = (q >> 4) * 128; n0 = (q & 15) * 64;
    int cnt = counts[e]; if (cnt > CAP) cnt = CAP;
    if (m0 >= cnt) return;
    Ap = hexp + (size_t)e * (CAP * DFF);
    Bp = w2t + (size_t)e * (DM * DFF);
    K = DFF;
  }

  __shared__ __align__(16) u16 As[128 * 64];
  __shared__ __align__(16) u16 Bs[64 * 64];

  uint32_t aoff[8], boff[4];
#pragma unroll
  for (int j = 0; j < 8; ++j) {
    int L = tid + 128 * j;
    int row = L >> 3;
    int c = (L & 7) ^ (row & 7);
    aoff[j] = (uint32_t)(m0 + row) * K + c * 8;
  }
#pragma unroll
  for (int j = 0; j < 4; ++j) {
    int L = tid + 128 * j;
    int row = L >> 3;
    int c = (L & 7) ^ (row & 7);
    boff[j] = (uint32_t)(n0 + row) * K + c * 8;
  }

  const int lane = tid & 63;
  const int wv = tid >> 6;
  const int wr = wv * 64;
  const int lr = lane & 15;
  const int lq = lane >> 4;

  f32x4 acc[4][4];
#pragma unroll
  for (int i = 0; i < 4; ++i)
#pragma unroll
    for (int j = 0; j < 4; ++j) acc[i][j] = (f32x4){0.f, 0.f, 0.f, 0.f};

  for (int k0 = 0; k0 < K; k0 += 64) {
    __syncthreads();
#pragma unroll
    for (int j = 0; j < 8; ++j) gl2lds16(Ap + aoff[j] + k0, &As[(size_t)(tid + 128 * j) * 8]);
#pragma unroll
    for (int j = 0; j < 4; ++j) gl2lds16(Bp + boff[j] + k0, &Bs[(size_t)(tid + 128 * j) * 8]);
    __syncthreads();
#pragma unroll
    for (int cc = 0; cc < 2; ++cc) {
      bf16x8 af[4], bfr[4];
#pragma unroll
      for (int i = 0; i < 4; ++i) af[i] = FRAG(As, wr + i * 16 + lr, cc);
#pragma unroll
      for (int j = 0; j < 4; ++j) bfr[j] = FRAG(Bs, j * 16 + lr, cc);
#pragma unroll
      for (int i = 0; i < 4; ++i)
#pragma unroll
        for (int j = 0; j < 4; ++j)
          acc[i][j] = __builtin_amdgcn_mfma_f32_16x16x32_bf16(af[i], bfr[j], acc[i][j], 0, 0, 0);
    }
  }

  if (e < 0) {
#pragma unroll
    for (int i = 0; i < 4; ++i)
#pragma unroll
      for (int r = 0; r < 4; ++r) {
        int row = m0 + wr + i * 16 + lq * 4 + r;
        float* orow = out + (size_t)row * DM;
#pragma unroll
        for (int j = 0; j < 4; ++j)
          orow[n0 + j * 16 + lr] = acc[i][j][r];
      }
  } else {
    u16* obase = ob + (size_t)e * CAP * DM;
#pragma unroll
    for (int i = 0; i < 4; ++i)
#pragma unroll
      for (int r = 0; r < 4; ++r) {
        int row = m0 + wr + i * 16 + lq * 4 + r;
        u16* orow = obase + (size_t)row * DM;
#pragma unroll
        for (int j = 0; j < 4; ++j)
          orow[n0 + j * 16 + lr] = f2bf(acc[i][j][r]);
      }
  }
}

// ============ COMBINE: out[t] += w0*ob[s0] + w1*ob[s1] ============
__global__ __launch_bounds__(256) void k_combine(
    float* __restrict__ out, const u16* __restrict__ ob,
    const int* __restrict__ tslot, const float* __restrict__ tw) {
  int t = blockIdx.x;
  int c = threadIdx.x * 4;
  int s0 = tslot[2 * t], s1 = tslot[2 * t + 1];
  float w0 = tw[2 * t], w1 = tw[2 * t + 1];
  float4 v = *(float4*)&out[(size_t)t * DM + c];
  if (s0 >= 0) {
    ushort4 o = *(const ushort4*)&ob[(size_t)s0 * DM + c];
    v.x += w0 * bf2f(o.x); v.y += w0 * bf2f(o.y);
    v.z += w0 * bf2f(o.z); v.w += w0 * bf2f(o.w);
  }
  if (s1 >= 0) {
    ushort4 o = *(const ushort4*)&ob[(size_t)s1 * DM + c];
    v.x += w1 * bf2f(o.x); v.y += w1 * bf2f(o.y);
    v.z += w1 * bf2f(o.z); v.w += w1 * bf2f(o.w);
  }
  *(float4*)&out[(size_t)t * DM + c] = v;
}

// ---------------- host ----------------
extern "C" void kernel_launch(void* const* d_in, const int* in_sizes, int n_in,
                              void* d_out, int out_size, void* d_ws, size_t ws_size,
                              hipStream_t stream) {
  (void)in_sizes; (void)n_in; (void)out_size; (void)ws_size;
  const float* x   = (const float*)d_in[0];
  const float* Wg  = (const float*)d_in[1];
  const float* w1  = (const float*)d_in[2];
  const float* w3  = (const float*)d_in[3];
  const float* w2  = (const float*)d_in[4];
  const float* ws1 = (const float*)d_in[5];
  const float* ws3 = (const float*)d_in[6];
  const float* ws2 = (const float*)d_in[7];
  float* out = (float*)d_out;
  char* ws = (char*)d_ws;

  u16* hbf   = (u16*)(ws + 0);          // 8 MB   [TT,DM] bf16          (dead after k_up)
  u16* w1t   = (u16*)(ws + 8388608);    // 16 MB  [E][DFF][DM]          (dead after k_up)
  u16* w3t   = (u16*)(ws + 25165824);   // 16 MB                        (dead after k_up)
  u16* w2t   = (u16*)(ws + 41943040);   // 16 MB  [E][DM][DFF]
  u16* ws1t  = (u16*)(ws + 58720256);   // 2 MB   [DFS][DM]
  u16* ws3t  = (u16*)(ws + 60817408);   // 2 MB
  u16* ws2t  = (u16*)(ws + 62914560);   // 2 MB   [DM][DFS]
  u16* hs    = (u16*)(ws + 65011712);   // 8 MB   [TT,DFS] bf16
  u16* hexp  = (u16*)(ws + 73400320);   // 16 MB  [E][CAP][DFF] bf16
  int* counts    = (int*)(ws + 90177536);
  int* tok_slot  = (int*)(ws + 90177792);   // 64 KB
  int* tslot     = (int*)(ws + 90243328);   // 32 KB [TT*2]
  float* tw      = (float*)(ws + 90276096); // 32 KB [TT*2]
  u16* ob    = (u16*)(ws + 0);          // 33.5 MB [E*CAP, DM] bf16 — aliases hbf/w1t/w3t
                                        // (written only in k_down, after those are dead)

  hipMemsetAsync(counts, 0, NE * sizeof(int), stream);

  // prep: 256 router blocks + 51*256 transpose blocks
  k_prep<<<dim3(256 + 51 * 256), dim3(256), 0, stream>>>(
      x, Wg, w1, w3, w2, ws1, ws3, ws2,
      hbf, w1t, w3t, w2t, ws1t, ws3t, ws2t,
      counts, tok_slot, tslot, tw);

  // up: 512 shared tiles (32m x 16n) + 1024 routed tiles (16e x 8m x 8n)
  k_up<<<dim3(512 + NE * 64), dim3(128), 0, stream>>>(
      hbf, ws1t, ws3t, w1t, w3t, hs, hexp, counts, tok_slot);

  // down: 512 shared tiles -> out (plain fp32) + 2048 routed tiles -> ob (plain bf16)
  k_down<<<dim3(512 + NE * 128), dim3(128), 0, stream>>>(
      hs, ws2t, hexp, w2t, out, ob, counts);

  // combine: out[t] += w0*ob[s0] + w1*ob[s1]
  k_combine<<<dim3(TT), dim3(256), 0, stream>>>(out, ob, tslot, tw);
}